// Round 2
// baseline (1076.908 us; speedup 1.0000x reference)
//
#include <hip/hip_runtime.h>

#define NTOK 8192
#define DIN 1024
#define DH   4096
#define DOUT 1024
#define NE   8
#define MAXTILES 136              // ceil-padded: 16384/128 + 8
#define SLOTCAP  (MAXTILES*128)   // 17408

typedef __bf16 bf16x8 __attribute__((ext_vector_type(8)));
typedef float  f32x4  __attribute__((ext_vector_type(4)));

// ---- workspace layout (bytes) ----
constexpr size_t OFF_W1T  = 0;                       // 8*1024*4096*2 = 67108864
constexpr size_t OFF_W2T  = 67108864;                // 67108864
constexpr size_t OFF_XB   = 134217728;               // 8192*1024*2 = 16777216
constexpr size_t OFF_H    = 150994944;               // 17408*4096*2 = 142606336
constexpr size_t OFF_SROW = 293601280;               // 17408*4
constexpr size_t OFF_SW   = 293670912;               // 17408*4
constexpr size_t OFF_TIDX = 293740544;               // 8192*2*4
constexpr size_t OFF_TW   = 293806080;               // 8192*2*4
constexpr size_t OFF_CTRL = 293871616;               // count[8] @0, fill[8] @32, tile_off[9] @64
constexpr size_t OFF_PART = 293871744;               // 2048*8*4 = 65536

__device__ __forceinline__ ushort f2bf(float f){
  unsigned u = __float_as_uint(f);
  u += 0x7fff + ((u >> 16) & 1);          // RNE
  return (ushort)(u >> 16);
}

#define GLDS(g,l) __builtin_amdgcn_global_load_lds( \
    (const __attribute__((address_space(1))) void*)(g), \
    (__attribute__((address_space(3))) void*)(l), 16, 0, 0)

// ---------------- x -> bf16 ----------------
__global__ void k_cvt_x(const float4* __restrict__ x, ushort4* __restrict__ xb){
  int i = blockIdx.x * 256 + threadIdx.x;
  float4 v = x[i];
  ushort4 o;
  o.x = f2bf(v.x); o.y = f2bf(v.y); o.z = f2bf(v.z); o.w = f2bf(v.w);
  xb[i] = o;
}

// ------------- W[E][R][C] f32 -> WT[E][C][R] bf16, vectorized -------------
__global__ void k_transpose(const float* __restrict__ W, ushort* __restrict__ WT, int R, int C){
  __shared__ ushort tl[64][72];       // +8 ushort pad: kills read-phase conflicts
  int e  = blockIdx.z;
  int r0 = blockIdx.x * 64, c0 = blockIdx.y * 64;
  const float* Wp  = W  + (size_t)e * R * C;
  ushort*      WTp = WT + (size_t)e * R * C;
  int t = threadIdx.x;
  int lr  = t >> 4;     // 0..15
  int lc4 = t & 15;     // 0..15  (float4 column group)
#pragma unroll
  for (int i = 0; i < 4; i++){
    int r = lr + i * 16;
    float4 v = *(const float4*)(Wp + (size_t)(r0 + r) * C + c0 + lc4 * 4);
    ushort4 o; o.x = f2bf(v.x); o.y = f2bf(v.y); o.z = f2bf(v.z); o.w = f2bf(v.w);
    *(ushort4*)&tl[r][lc4 * 4] = o;
  }
  __syncthreads();
  int tr4 = t & 15;     // chunk along R (out-contiguous dim)
  int tcc = t >> 4;     // 0..15
#pragma unroll
  for (int i = 0; i < 4; i++){
    int c = tcc + i * 16;
    ushort4 o;
    o.x = tl[tr4 * 4 + 0][c]; o.y = tl[tr4 * 4 + 1][c];
    o.z = tl[tr4 * 4 + 2][c]; o.w = tl[tr4 * 4 + 3][c];
    *(ushort4*)(WTp + (size_t)(c0 + c) * R + r0 + tr4 * 4) = o;
  }
}

// ---------------- gate: logits, softmax, top-2, counts ----------------
__global__ void k_gate(const float* __restrict__ x, const float* __restrict__ gw,
                       const float* __restrict__ gb, float* __restrict__ probs_out,
                       int* __restrict__ topk_idx, float* __restrict__ topk_w,
                       int* __restrict__ count, float* __restrict__ partial){
  __shared__ float psum[8];
  __shared__ int   pcnt[8];
  int wv = threadIdx.x >> 6, lane = threadIdx.x & 63;
  int row = blockIdx.x * 4 + wv;
  if (threadIdx.x < 8){ psum[threadIdx.x] = 0.f; pcnt[threadIdx.x] = 0; }
  __syncthreads();

  const float4* x4 = (const float4*)(x + (size_t)row * DIN);
  float acc[8];
#pragma unroll
  for (int e = 0; e < 8; e++) acc[e] = 0.f;
#pragma unroll
  for (int j = 0; j < 4; j++){
    float4 v = x4[j * 64 + lane];
    int kbase = (j * 64 + lane) * 4;
#pragma unroll
    for (int c = 0; c < 4; c++){
      float xv = (&v.x)[c];
      const float4* g4 = (const float4*)(gw + (size_t)(kbase + c) * 8);
      float4 g0 = g4[0], g1 = g4[1];
      acc[0] += xv * g0.x; acc[1] += xv * g0.y; acc[2] += xv * g0.z; acc[3] += xv * g0.w;
      acc[4] += xv * g1.x; acc[5] += xv * g1.y; acc[6] += xv * g1.z; acc[7] += xv * g1.w;
    }
  }
#pragma unroll
  for (int e = 0; e < 8; e++)
#pragma unroll
    for (int off = 32; off; off >>= 1) acc[e] += __shfl_xor(acc[e], off, 64);

  float lg[8], p[8], mx = -1e30f, s = 0.f;
#pragma unroll
  for (int e = 0; e < 8; e++){ lg[e] = acc[e] + gb[e]; mx = fmaxf(mx, lg[e]); }
#pragma unroll
  for (int e = 0; e < 8; e++){ p[e] = expf(lg[e] - mx); s += p[e]; }
  float inv = 1.f / s;
#pragma unroll
  for (int e = 0; e < 8; e++) p[e] *= inv;

  if (lane < 8) probs_out[(size_t)row * 8 + lane] = p[lane];

  if (lane == 0){
    int i1 = 0; float v1 = p[0];
#pragma unroll
    for (int e = 1; e < 8; e++) if (p[e] > v1){ v1 = p[e]; i1 = e; }
    int i2 = -1; float v2 = -1.f;
#pragma unroll
    for (int e = 0; e < 8; e++){ if (e == i1) continue; if (p[e] > v2){ v2 = p[e]; i2 = e; } }
    float denom = 1.f / (v1 + v2 + 1e-10f);
    topk_idx[row * 2]     = i1;  topk_idx[row * 2 + 1] = i2;
    topk_w  [row * 2]     = v1 * denom;  topk_w[row * 2 + 1] = v2 * denom;
    atomicAdd(&pcnt[i1], 1); atomicAdd(&pcnt[i2], 1);
  }
  if (lane < 8) atomicAdd(&psum[lane], p[lane]);
  __syncthreads();
  if (threadIdx.x < 8){
    partial[(size_t)blockIdx.x * 8 + threadIdx.x] = psum[threadIdx.x];
    if (pcnt[threadIdx.x]) atomicAdd(&count[threadIdx.x], pcnt[threadIdx.x]);
  }
}

// ---------------- aux loss + tile offsets ----------------
__global__ void k_aux(const float* __restrict__ partial, const int* __restrict__ count,
                      float* __restrict__ aux_out, int* __restrict__ tile_off){
  __shared__ float red[256];
  __shared__ float tot[8];
  int t = threadIdx.x, e = t & 7;
  float s = 0.f;
  for (int b = (t >> 3); b < 2048; b += 32) s += partial[(size_t)b * 8 + e];
  red[t] = s; __syncthreads();
  if (t < 8){ float v = 0.f; for (int c = 0; c < 32; c++) v += red[c * 8 + t]; tot[t] = v; }
  __syncthreads();
  if (t == 0){
    float aux = 0.f;
    for (int i = 0; i < 8; i++){
      float m = tot[i] * (1.f / 8192.f);
      aux += m * logf(m * 8.f + 1e-10f);
    }
    aux_out[0] = aux;
    int off = 0;
    for (int i = 0; i < 8; i++){ tile_off[i] = off; off += (count[i] + 127) >> 7; }
    tile_off[8] = off;
  }
}

// ---------------- scatter assignments into padded slots ----------------
__global__ void k_scatter(const int* __restrict__ topk_idx, const float* __restrict__ topk_w,
                          const int* __restrict__ tile_off, int* __restrict__ fill,
                          int* __restrict__ slot_row, float* __restrict__ slot_w){
  int i = blockIdx.x * 256 + threadIdx.x;
  int row = i >> 1;
  int e = topk_idx[i];
  float w = topk_w[i];
  int lane = threadIdx.x & 63;
  int pos = 0;
#pragma unroll
  for (int ex = 0; ex < 8; ex++){
    unsigned long long mask = __ballot(e == ex);
    if (e == ex){
      int leader = __ffsll((long long)mask) - 1;
      int base = 0;
      if (lane == leader) base = atomicAdd(&fill[ex], (int)__popcll(mask));
      base = __shfl(base, leader, 64);
      pos = base + (int)__popcll(mask & ((1ull << lane) - 1ull));
    }
  }
  int slot = tile_off[e] * 128 + pos;
  slot_row[slot] = row;
  slot_w[slot]   = w;
}

// =================================================================
// GEMM core: BM=BN=128, BK=64, 256 threads (2x2 waves, 4x4 MFMA 16x16x32
// each). LDS rows are 128B (one full bank line); 16B chunk position is
// XOR-swizzled with (row&7) so ds_read_b128 fragment reads tile the banks
// exactly (2 lanes/bank-group = free).
// =================================================================

// ---------------- GEMM1: H = relu(X_gathered @ w1t^T + b1), bf16 out ----------------
__global__ __launch_bounds__(256, 4) void k_gemm1(
    const ushort* __restrict__ xb, const ushort* __restrict__ w1t,
    const float* __restrict__ b1, const int* __restrict__ slot_row,
    const int* __restrict__ tile_off, ushort* __restrict__ H){
  __shared__ ushort As[128 * 64];
  __shared__ ushort Bs[128 * 64];
  // panel-swizzled 1-D grid: 17 panels x (8 m-tiles x 32 n-tiles)
  int id = blockIdx.x;
  int pid = id >> 8, w = id & 255;
  int tileN = w & 31;               // fastest: id%8 tracks XCD -> L2 owns B column
  int tileM = pid * 8 + (w >> 5);
  if (tileM >= tile_off[8]) return;
  int e = 0;
  while (e < 7 && tile_off[e + 1] <= tileM) e++;
  int m0 = tileM * 128, n0 = tileN * 128;
  int t = threadIdx.x;

  const ushort* aPtr[4]; const ushort* bPtr[4];
#pragma unroll
  for (int i = 0; i < 4; i++){
    int c = i * 256 + t, r = c >> 3, qp = c & 7;
    int q = qp ^ (r & 7);                       // swizzled source chunk
    aPtr[i] = xb  + (size_t)slot_row[m0 + r] * DIN + q * 8;
    bPtr[i] = w1t + ((size_t)e * DH + n0 + r) * DIN + q * 8;
  }
  int wv = t >> 6, lane = t & 63;
  int wm = wv >> 1, wn = wv & 1, quad = lane >> 4, lc = lane & 15;
  f32x4 acc[4][4] = {};

  for (int k0 = 0; k0 < DIN; k0 += 64){
#pragma unroll
    for (int i = 0; i < 4; i++){
      int c = i * 256 + t;
      GLDS(aPtr[i] + k0, As + c * 8);
      GLDS(bPtr[i] + k0, Bs + c * 8);
    }
    __syncthreads();
#pragma unroll
    for (int kk = 0; kk < 2; kk++){
      bf16x8 a[4], b[4];
#pragma unroll
      for (int z = 0; z < 4; z++){
        int ra = wm * 64 + z * 16 + lc;
        a[z] = *(const bf16x8*)(As + ra * 64 + (((kk * 4 + quad) ^ (ra & 7)) * 8));
        int rb = wn * 64 + z * 16 + lc;
        b[z] = *(const bf16x8*)(Bs + rb * 64 + (((kk * 4 + quad) ^ (rb & 7)) * 8));
      }
#pragma unroll
      for (int zi = 0; zi < 4; zi++)
#pragma unroll
        for (int zj = 0; zj < 4; zj++)
          acc[zi][zj] = __builtin_amdgcn_mfma_f32_16x16x32_bf16(a[zi], b[zj], acc[zi][zj], 0, 0, 0);
    }
    __syncthreads();
  }

  const float* b1e = b1 + (size_t)e * DH;
#pragma unroll
  for (int i = 0; i < 4; i++){
#pragma unroll
    for (int r = 0; r < 4; r++){
      int slot = m0 + wm * 64 + i * 16 + quad * 4 + r;
      ushort* hrow = H + (size_t)slot * DH;
#pragma unroll
      for (int j = 0; j < 4; j++){
        int col = n0 + wn * 64 + j * 16 + lc;
        float v = acc[i][j][r] + b1e[col];
        hrow[col] = f2bf(fmaxf(v, 0.f));
      }
    }
  }
}

// ---------------- GEMM2: out[row] += w * (H @ w2t^T + b2) ----------------
__global__ __launch_bounds__(256, 4) void k_gemm2(
    const ushort* __restrict__ H, const ushort* __restrict__ w2t,
    const float* __restrict__ b2, const int* __restrict__ slot_row,
    const float* __restrict__ slot_w, const int* __restrict__ tile_off,
    float* __restrict__ out){
  __shared__ ushort As[128 * 64];
  __shared__ ushort Bs[128 * 64];
  // panel-swizzled 1-D grid: 8.5 panels x (16 m-tiles x 8 n-tiles)
  int id = blockIdx.x;
  int pid = id >> 7, w = id & 127;
  int tileN = w & 7;                // fastest: id%8 tracks XCD
  int tileM = pid * 16 + (w >> 3);
  if (tileM >= tile_off[8]) return;
  int e = 0;
  while (e < 7 && tile_off[e + 1] <= tileM) e++;
  int m0 = tileM * 128, n0 = tileN * 128;
  int t = threadIdx.x;

  const ushort* aPtr[4]; const ushort* bPtr[4];
#pragma unroll
  for (int i = 0; i < 4; i++){
    int c = i * 256 + t, r = c >> 3, qp = c & 7;
    int q = qp ^ (r & 7);
    aPtr[i] = H   + (size_t)(m0 + r) * DH + q * 8;
    bPtr[i] = w2t + ((size_t)e * DOUT + n0 + r) * DH + q * 8;
  }
  int wv = t >> 6, lane = t & 63;
  int wm = wv >> 1, wn = wv & 1, quad = lane >> 4, lc = lane & 15;
  f32x4 acc[4][4] = {};

  for (int k0 = 0; k0 < DH; k0 += 64){
#pragma unroll
    for (int i = 0; i < 4; i++){
      int c = i * 256 + t;
      GLDS(aPtr[i] + k0, As + c * 8);
      GLDS(bPtr[i] + k0, Bs + c * 8);
    }
    __syncthreads();
#pragma unroll
    for (int kk = 0; kk < 2; kk++){
      bf16x8 a[4], b[4];
#pragma unroll
      for (int z = 0; z < 4; z++){
        int ra = wm * 64 + z * 16 + lc;
        a[z] = *(const bf16x8*)(As + ra * 64 + (((kk * 4 + quad) ^ (ra & 7)) * 8));
        int rb = wn * 64 + z * 16 + lc;
        b[z] = *(const bf16x8*)(Bs + rb * 64 + (((kk * 4 + quad) ^ (rb & 7)) * 8));
      }
#pragma unroll
      for (int zi = 0; zi < 4; zi++)
#pragma unroll
        for (int zj = 0; zj < 4; zj++)
          acc[zi][zj] = __builtin_amdgcn_mfma_f32_16x16x32_bf16(a[zi], b[zj], acc[zi][zj], 0, 0, 0);
    }
    __syncthreads();
  }

  const float* b2e = b2 + (size_t)e * DOUT;
#pragma unroll
  for (int i = 0; i < 4; i++){
#pragma unroll
    for (int r = 0; r < 4; r++){
      int slot = m0 + wm * 64 + i * 16 + quad * 4 + r;
      float w2 = slot_w[slot];
      if (w2 == 0.f) continue;
      float* orow = out + (size_t)slot_row[slot] * DOUT;
#pragma unroll
      for (int j = 0; j < 4; j++){
        int col = n0 + wn * 64 + j * 16 + lc;
        atomicAdd(orow + col, w2 * (acc[i][j][r] + b2e[col]));
      }
    }
  }
}

extern "C" void kernel_launch(void* const* d_in, const int* in_sizes, int n_in,
                              void* d_out, int out_size, void* d_ws, size_t ws_size,
                              hipStream_t stream){
  const float* x      = (const float*)d_in[0];
  const float* gate_w = (const float*)d_in[1];
  const float* gate_b = (const float*)d_in[2];
  const float* w1     = (const float*)d_in[3];
  const float* b1     = (const float*)d_in[4];
  const float* w2     = (const float*)d_in[5];
  const float* b2     = (const float*)d_in[6];
  float* out = (float*)d_out;

  char* ws = (char*)d_ws;
  ushort* W1T   = (ushort*)(ws + OFF_W1T);
  ushort* W2T   = (ushort*)(ws + OFF_W2T);
  ushort* XB    = (ushort*)(ws + OFF_XB);
  ushort* H     = (ushort*)(ws + OFF_H);
  int*    SROW  = (int*)   (ws + OFF_SROW);
  float*  SW    = (float*) (ws + OFF_SW);
  int*    TIDX  = (int*)   (ws + OFF_TIDX);
  float*  TW    = (float*) (ws + OFF_TW);
  int*    COUNT = (int*)   (ws + OFF_CTRL);
  int*    FILL  = (int*)   (ws + OFF_CTRL + 32);
  int*    TOFF  = (int*)   (ws + OFF_CTRL + 64);
  float*  PART  = (float*) (ws + OFF_PART);

  float* aux_out   = out + (size_t)NTOK * DOUT;
  float* probs_out = aux_out + 1;

  hipMemsetAsync(d_out, 0, (size_t)out_size * 4, stream);
  hipMemsetAsync(ws + OFF_CTRL, 0, 128, stream);
  hipMemsetAsync(ws + OFF_SROW, 0, (size_t)SLOTCAP * 8, stream);

  k_cvt_x<<<dim3((NTOK * DIN / 4) / 256), 256, 0, stream>>>((const float4*)x, (ushort4*)XB);
  k_transpose<<<dim3(DIN / 64, DH / 64, NE), 256, 0, stream>>>(w1, W1T, DIN, DH);
  k_transpose<<<dim3(DH / 64, DOUT / 64, NE), 256, 0, stream>>>(w2, W2T, DH, DOUT);
  k_gate<<<dim3(NTOK / 4), 256, 0, stream>>>(x, gate_w, gate_b, probs_out, TIDX, TW, COUNT, PART);
  k_aux<<<dim3(1), 256, 0, stream>>>(PART, COUNT, aux_out, TOFF);
  k_scatter<<<dim3(NTOK * 2 / 256), 256, 0, stream>>>(TIDX, TW, TOFF, FILL, SROW, SW);
  k_gemm1<<<dim3(MAXTILES * (DH / 128)), 256, 0, stream>>>(XB, W1T, b1, SROW, TOFF, H);
  k_gemm2<<<dim3(MAXTILES * (DOUT / 128)), 256, 0, stream>>>(H, W2T, b2, SROW, SW, TOFF, out);
}

// Round 3
// 1047.701 us; speedup vs baseline: 1.0279x; 1.0279x over previous
//
#include <hip/hip_runtime.h>

#define NTOK 8192
#define DIN 1024
#define DH   4096
#define DOUT 1024
#define NE   8
#define MAXT256  72               // ceil(16384/256) + 8 experts worst-case pad
#define SLOTCAP  (MAXT256*256)    // 18432

typedef __bf16 bf16x8 __attribute__((ext_vector_type(8)));
typedef float  f32x16 __attribute__((ext_vector_type(16)));

// ---- workspace layout (bytes); total 235,225,216 (< 294 MB known-safe) ----
constexpr size_t OFF_WT   = 0;                 // 64 MB, shared: W1T before gemm1, W2T after
constexpr size_t OFF_XB   = 67108864;          // 16 MB
constexpr size_t OFF_SROW = 83886080;          // 18432*4
constexpr size_t OFF_SW   = 83959808;          // 18432*4
constexpr size_t OFF_TIDX = 84033536;          // 65536
constexpr size_t OFF_TW   = 84099072;          // 65536
constexpr size_t OFF_CTRL = 84164608;          // count[8]@0, fill[8]@32, tile_off[9]@64
constexpr size_t OFF_PART = 84164736;          // 65536
constexpr size_t OFF_H    = 84230272;          // 18432*4096*2 = 150,994,944

__device__ __forceinline__ ushort f2bf(float f){
  unsigned u = __float_as_uint(f);
  u += 0x7fff + ((u >> 16) & 1);          // RNE
  return (ushort)(u >> 16);
}

#define GLDS(g,l) __builtin_amdgcn_global_load_lds( \
    (const __attribute__((address_space(1))) void*)(g), \
    (__attribute__((address_space(3))) void*)(l), 16, 0, 0)

// ---------------- x -> bf16 ----------------
__global__ void k_cvt_x(const float4* __restrict__ x, ushort4* __restrict__ xb){
  int i = blockIdx.x * 256 + threadIdx.x;
  float4 v = x[i];
  ushort4 o;
  o.x = f2bf(v.x); o.y = f2bf(v.y); o.z = f2bf(v.z); o.w = f2bf(v.w);
  xb[i] = o;
}

// ------------- W[E][R][C] f32 -> WT[E][C][R] bf16, vectorized -------------
__global__ void k_transpose(const float* __restrict__ W, ushort* __restrict__ WT, int R, int C){
  __shared__ ushort tl[64][72];
  int e  = blockIdx.z;
  int r0 = blockIdx.x * 64, c0 = blockIdx.y * 64;
  const float* Wp  = W  + (size_t)e * R * C;
  ushort*      WTp = WT + (size_t)e * R * C;
  int t = threadIdx.x;
  int lr  = t >> 4;
  int lc4 = t & 15;
#pragma unroll
  for (int i = 0; i < 4; i++){
    int r = lr + i * 16;
    float4 v = *(const float4*)(Wp + (size_t)(r0 + r) * C + c0 + lc4 * 4);
    ushort4 o; o.x = f2bf(v.x); o.y = f2bf(v.y); o.z = f2bf(v.z); o.w = f2bf(v.w);
    *(ushort4*)&tl[r][lc4 * 4] = o;
  }
  __syncthreads();
  int tr4 = t & 15;
  int tcc = t >> 4;
#pragma unroll
  for (int i = 0; i < 4; i++){
    int c = tcc + i * 16;
    ushort4 o;
    o.x = tl[tr4 * 4 + 0][c]; o.y = tl[tr4 * 4 + 1][c];
    o.z = tl[tr4 * 4 + 2][c]; o.w = tl[tr4 * 4 + 3][c];
    *(ushort4*)(WTp + (size_t)(c0 + c) * R + r0 + tr4 * 4) = o;
  }
}

// ---------------- gate: logits, softmax, top-2, counts ----------------
__global__ void k_gate(const float* __restrict__ x, const float* __restrict__ gw,
                       const float* __restrict__ gb, float* __restrict__ probs_out,
                       int* __restrict__ topk_idx, float* __restrict__ topk_w,
                       int* __restrict__ count, float* __restrict__ partial){
  __shared__ float psum[8];
  __shared__ int   pcnt[8];
  int wv = threadIdx.x >> 6, lane = threadIdx.x & 63;
  int row = blockIdx.x * 4 + wv;
  if (threadIdx.x < 8){ psum[threadIdx.x] = 0.f; pcnt[threadIdx.x] = 0; }
  __syncthreads();

  const float4* x4 = (const float4*)(x + (size_t)row * DIN);
  float acc[8];
#pragma unroll
  for (int e = 0; e < 8; e++) acc[e] = 0.f;
#pragma unroll
  for (int j = 0; j < 4; j++){
    float4 v = x4[j * 64 + lane];
    int kbase = (j * 64 + lane) * 4;
#pragma unroll
    for (int c = 0; c < 4; c++){
      float xv = (&v.x)[c];
      const float4* g4 = (const float4*)(gw + (size_t)(kbase + c) * 8);
      float4 g0 = g4[0], g1 = g4[1];
      acc[0] += xv * g0.x; acc[1] += xv * g0.y; acc[2] += xv * g0.z; acc[3] += xv * g0.w;
      acc[4] += xv * g1.x; acc[5] += xv * g1.y; acc[6] += xv * g1.z; acc[7] += xv * g1.w;
    }
  }
#pragma unroll
  for (int e = 0; e < 8; e++)
#pragma unroll
    for (int off = 32; off; off >>= 1) acc[e] += __shfl_xor(acc[e], off, 64);

  float lg[8], p[8], mx = -1e30f, s = 0.f;
#pragma unroll
  for (int e = 0; e < 8; e++){ lg[e] = acc[e] + gb[e]; mx = fmaxf(mx, lg[e]); }
#pragma unroll
  for (int e = 0; e < 8; e++){ p[e] = expf(lg[e] - mx); s += p[e]; }
  float inv = 1.f / s;
#pragma unroll
  for (int e = 0; e < 8; e++) p[e] *= inv;

  if (lane < 8) probs_out[(size_t)row * 8 + lane] = p[lane];

  if (lane == 0){
    int i1 = 0; float v1 = p[0];
#pragma unroll
    for (int e = 1; e < 8; e++) if (p[e] > v1){ v1 = p[e]; i1 = e; }
    int i2 = -1; float v2 = -1.f;
#pragma unroll
    for (int e = 0; e < 8; e++){ if (e == i1) continue; if (p[e] > v2){ v2 = p[e]; i2 = e; } }
    float denom = 1.f / (v1 + v2 + 1e-10f);
    topk_idx[row * 2]     = i1;  topk_idx[row * 2 + 1] = i2;
    topk_w  [row * 2]     = v1 * denom;  topk_w[row * 2 + 1] = v2 * denom;
    atomicAdd(&pcnt[i1], 1); atomicAdd(&pcnt[i2], 1);
  }
  if (lane < 8) atomicAdd(&psum[lane], p[lane]);
  __syncthreads();
  if (threadIdx.x < 8){
    partial[(size_t)blockIdx.x * 8 + threadIdx.x] = psum[threadIdx.x];
    if (pcnt[threadIdx.x]) atomicAdd(&count[threadIdx.x], pcnt[threadIdx.x]);
  }
}

// ---------------- aux loss + tile offsets (256-row tiles) ----------------
__global__ void k_aux(const float* __restrict__ partial, const int* __restrict__ count,
                      float* __restrict__ aux_out, int* __restrict__ tile_off){
  __shared__ float red[256];
  __shared__ float tot[8];
  int t = threadIdx.x, e = t & 7;
  float s = 0.f;
  for (int b = (t >> 3); b < 2048; b += 32) s += partial[(size_t)b * 8 + e];
  red[t] = s; __syncthreads();
  if (t < 8){ float v = 0.f; for (int c = 0; c < 32; c++) v += red[c * 8 + t]; tot[t] = v; }
  __syncthreads();
  if (t == 0){
    float aux = 0.f;
    for (int i = 0; i < 8; i++){
      float m = tot[i] * (1.f / 8192.f);
      aux += m * logf(m * 8.f + 1e-10f);
    }
    aux_out[0] = aux;
    int off = 0;
    for (int i = 0; i < 8; i++){ tile_off[i] = off; off += (count[i] + 255) >> 8; }
    tile_off[8] = off;
  }
}

// ---------------- scatter assignments into 256-padded slots ----------------
__global__ void k_scatter(const int* __restrict__ topk_idx, const float* __restrict__ topk_w,
                          const int* __restrict__ tile_off, int* __restrict__ fill,
                          int* __restrict__ slot_row, float* __restrict__ slot_w){
  int i = blockIdx.x * 256 + threadIdx.x;
  int row = i >> 1;
  int e = topk_idx[i];
  float w = topk_w[i];
  int lane = threadIdx.x & 63;
  int pos = 0;
#pragma unroll
  for (int ex = 0; ex < 8; ex++){
    unsigned long long mask = __ballot(e == ex);
    if (e == ex){
      int leader = __ffsll((long long)mask) - 1;
      int base = 0;
      if (lane == leader) base = atomicAdd(&fill[ex], (int)__popcll(mask));
      base = __shfl(base, leader, 64);
      pos = base + (int)__popcll(mask & ((1ull << lane) - 1ull));
    }
  }
  int slot = tile_off[e] * 256 + pos;
  slot_row[slot] = row;
  slot_w[slot]   = w;
}

// =================================================================
// GEMM core: BM=BN=256, BK=64, 512 threads (2x4 waves), each wave a
// 128x64 patch via 4x2 tiles of v_mfma_f32_32x32x16_bf16 (f32x16 acc).
// LDS rows 128B; 16B chunk XOR-8 swizzled (round-2 verified: 0 conflicts).
// AI = 128 FLOP/B -> halves staging demand vs 128-tiles (the round-2 wall).
// =================================================================

// ---------------- GEMM1: H = relu(X_gathered @ w1t^T + b1), bf16 out ----------------
__global__ __launch_bounds__(512, 2) void k_gemm1(
    const ushort* __restrict__ xb, const ushort* __restrict__ w1t,
    const float* __restrict__ b1, const int* __restrict__ slot_row,
    const int* __restrict__ tile_off, ushort* __restrict__ H){
  __shared__ ushort As[256 * 64];
  __shared__ ushort Bs[256 * 64];
  int id = blockIdx.x;
  int tileN = id & 15, tileM = id >> 4;    // id%8 spreads n across XCDs
  if (tileM >= tile_off[8]) return;
  int e = 0;
  while (e < 7 && tile_off[e + 1] <= tileM) e++;
  int m0 = tileM * 256, n0 = tileN * 256;
  int t = threadIdx.x;

  const ushort* aP[4]; const ushort* bP[4];
#pragma unroll
  for (int i = 0; i < 4; i++){
    int c = i * 512 + t, r = c >> 3, q = (c & 7) ^ (r & 7);
    aP[i] = xb  + (size_t)slot_row[m0 + r] * DIN + q * 8;
    bP[i] = w1t + ((size_t)e * DH + n0 + r) * DIN + q * 8;
  }
  int wv = t >> 6, lane = t & 63;
  int wm = wv >> 2, wn = wv & 3;           // 2 x 4 waves
  int lr = lane & 31, lk = lane >> 5;      // row-in-32, k-half
  f32x16 acc[4][2] = {};

  for (int k0 = 0; k0 < DIN; k0 += 64){
#pragma unroll
    for (int i = 0; i < 4; i++){
      int c = i * 512 + t;
      GLDS(aP[i] + k0, As + c * 8);
      GLDS(bP[i] + k0, Bs + c * 8);
    }
    __syncthreads();
#pragma unroll
    for (int kk = 0; kk < 4; kk++){
      bf16x8 a[4], b[2];
#pragma unroll
      for (int mi = 0; mi < 4; mi++){
        int r = wm * 128 + mi * 32 + lr;
        a[mi] = *(const bf16x8*)(As + r * 64 + (((kk * 2 + lk) ^ (r & 7)) * 8));
      }
#pragma unroll
      for (int nj = 0; nj < 2; nj++){
        int r = wn * 64 + nj * 32 + lr;
        b[nj] = *(const bf16x8*)(Bs + r * 64 + (((kk * 2 + lk) ^ (r & 7)) * 8));
      }
#pragma unroll
      for (int mi = 0; mi < 4; mi++)
#pragma unroll
        for (int nj = 0; nj < 2; nj++)
          acc[mi][nj] = __builtin_amdgcn_mfma_f32_32x32x16_bf16(a[mi], b[nj], acc[mi][nj], 0, 0, 0);
    }
    __syncthreads();
  }

  const float* b1e = b1 + (size_t)e * DH;
#pragma unroll
  for (int mi = 0; mi < 4; mi++){
#pragma unroll
    for (int nj = 0; nj < 2; nj++){
      int col = n0 + wn * 64 + nj * 32 + lr;
      float bias = b1e[col];
#pragma unroll
      for (int reg = 0; reg < 16; reg++){
        int row = (reg & 3) + 8 * (reg >> 2) + 4 * lk;     // m74/m101 C/D layout
        int slot = m0 + wm * 128 + mi * 32 + row;
        float v = acc[mi][nj][reg] + bias;
        H[(size_t)slot * DH + col] = f2bf(fmaxf(v, 0.f));
      }
    }
  }
}

// ---------------- GEMM2: out[row] += w * (H @ w2t^T + b2) ----------------
__global__ __launch_bounds__(512, 2) void k_gemm2(
    const ushort* __restrict__ H, const ushort* __restrict__ w2t,
    const float* __restrict__ b2, const int* __restrict__ slot_row,
    const float* __restrict__ slot_w, const int* __restrict__ tile_off,
    float* __restrict__ out){
  __shared__ ushort As[256 * 64];
  __shared__ ushort Bs[256 * 64];
  int id = blockIdx.x;
  int tileN = id & 3, tileM = id >> 2;
  if (tileM >= tile_off[8]) return;
  int e = 0;
  while (e < 7 && tile_off[e + 1] <= tileM) e++;
  int m0 = tileM * 256, n0 = tileN * 256;
  int t = threadIdx.x;

  const ushort* aP[4]; const ushort* bP[4];
#pragma unroll
  for (int i = 0; i < 4; i++){
    int c = i * 512 + t, r = c >> 3, q = (c & 7) ^ (r & 7);
    aP[i] = H   + (size_t)(m0 + r) * DH + q * 8;
    bP[i] = w2t + ((size_t)e * DOUT + n0 + r) * DH + q * 8;
  }
  int wv = t >> 6, lane = t & 63;
  int wm = wv >> 2, wn = wv & 3;
  int lr = lane & 31, lk = lane >> 5;
  f32x16 acc[4][2] = {};

  for (int k0 = 0; k0 < DH; k0 += 64){
#pragma unroll
    for (int i = 0; i < 4; i++){
      int c = i * 512 + t;
      GLDS(aP[i] + k0, As + c * 8);
      GLDS(bP[i] + k0, Bs + c * 8);
    }
    __syncthreads();
#pragma unroll
    for (int kk = 0; kk < 4; kk++){
      bf16x8 a[4], b[2];
#pragma unroll
      for (int mi = 0; mi < 4; mi++){
        int r = wm * 128 + mi * 32 + lr;
        a[mi] = *(const bf16x8*)(As + r * 64 + (((kk * 2 + lk) ^ (r & 7)) * 8));
      }
#pragma unroll
      for (int nj = 0; nj < 2; nj++){
        int r = wn * 64 + nj * 32 + lr;
        b[nj] = *(const bf16x8*)(Bs + r * 64 + (((kk * 2 + lk) ^ (r & 7)) * 8));
      }
#pragma unroll
      for (int mi = 0; mi < 4; mi++)
#pragma unroll
        for (int nj = 0; nj < 2; nj++)
          acc[mi][nj] = __builtin_amdgcn_mfma_f32_32x32x16_bf16(a[mi], b[nj], acc[mi][nj], 0, 0, 0);
    }
    __syncthreads();
  }

  const float* b2e = b2 + (size_t)e * DOUT;
#pragma unroll
  for (int mi = 0; mi < 4; mi++){
#pragma unroll
    for (int reg = 0; reg < 16; reg++){
      int row = (reg & 3) + 8 * (reg >> 2) + 4 * lk;
      int slot = m0 + wm * 128 + mi * 32 + row;
      float w = slot_w[slot];
      if (w == 0.f) continue;
      float* orow = out + (size_t)slot_row[slot] * DOUT;
#pragma unroll
      for (int nj = 0; nj < 2; nj++){
        int col = n0 + wn * 64 + nj * 32 + lr;
        atomicAdd(orow + col, w * (acc[mi][nj][reg] + b2e[col]));
      }
    }
  }
}

extern "C" void kernel_launch(void* const* d_in, const int* in_sizes, int n_in,
                              void* d_out, int out_size, void* d_ws, size_t ws_size,
                              hipStream_t stream){
  const float* x      = (const float*)d_in[0];
  const float* gate_w = (const float*)d_in[1];
  const float* gate_b = (const float*)d_in[2];
  const float* w1     = (const float*)d_in[3];
  const float* b1     = (const float*)d_in[4];
  const float* w2     = (const float*)d_in[5];
  const float* b2     = (const float*)d_in[6];
  float* out = (float*)d_out;

  char* ws = (char*)d_ws;
  ushort* WT    = (ushort*)(ws + OFF_WT);      // w1t, then w2t (reused)
  ushort* XB    = (ushort*)(ws + OFF_XB);
  ushort* H     = (ushort*)(ws + OFF_H);
  int*    SROW  = (int*)   (ws + OFF_SROW);
  float*  SW    = (float*) (ws + OFF_SW);
  int*    TIDX  = (int*)   (ws + OFF_TIDX);
  float*  TW    = (float*) (ws + OFF_TW);
  int*    COUNT = (int*)   (ws + OFF_CTRL);
  int*    FILL  = (int*)   (ws + OFF_CTRL + 32);
  int*    TOFF  = (int*)   (ws + OFF_CTRL + 64);
  float*  PART  = (float*) (ws + OFF_PART);

  float* aux_out   = out + (size_t)NTOK * DOUT;
  float* probs_out = aux_out + 1;

  hipMemsetAsync(d_out, 0, (size_t)out_size * 4, stream);
  hipMemsetAsync(ws + OFF_CTRL, 0, 128, stream);
  hipMemsetAsync(ws + OFF_SROW, 0, (size_t)SLOTCAP * 8, stream);  // slot_row + slot_w

  k_cvt_x<<<dim3((NTOK * DIN / 4) / 256), 256, 0, stream>>>((const float4*)x, (ushort4*)XB);
  k_transpose<<<dim3(DIN / 64, DH / 64, NE), 256, 0, stream>>>(w1, WT, DIN, DH);
  k_gate<<<dim3(NTOK / 4), 256, 0, stream>>>(x, gate_w, gate_b, probs_out, TIDX, TW, COUNT, PART);
  k_aux<<<dim3(1), 256, 0, stream>>>(PART, COUNT, aux_out, TOFF);
  k_scatter<<<dim3(NTOK * 2 / 256), 256, 0, stream>>>(TIDX, TW, TOFF, FILL, SROW, SW);
  k_gemm1<<<dim3(MAXT256 * (DH / 256)), 512, 0, stream>>>(XB, WT, b1, SROW, TOFF, H);
  k_transpose<<<dim3(DH / 64, DOUT / 64, NE), 256, 0, stream>>>(w2, WT, DH, DOUT);
  k_gemm2<<<dim3(MAXT256 * (DOUT / 256)), 512, 0, stream>>>(H, WT, b2, SROW, SW, TOFF, out);
}